// Round 2
// baseline (357.784 us; speedup 1.0000x reference)
//
#include <hip/hip_runtime.h>
#include <hip/hip_bf16.h>

// Problem constants (fixed shapes from setup_inputs)
static constexpr int N = 2048;
static constexpr int D = 128;
static constexpr int F = 8;
static constexpr int KC = 384;   // concat K: [hi|hi|lo] x [hi|lo|hi] = hh+hl+lh
static constexpr int BK = 64;

// ---------------- workspace layout (bytes) ----------------
static constexpr size_t OFF_LOSS  = 0;
static constexpr size_t OFF_KSIM  = 1024;
static constexpr size_t OFF_KLAB  = 132096;
static constexpr size_t OFF_RNQ   = 263168;
static constexpr size_t OFF_RND   = 328704;
static constexpr size_t OFF_DIAGS = 394240;
static constexpr size_t OFF_DIAGL = 459776;
static constexpr size_t OFF_QC    = 525312;                         // bf16 [F][N][KC]
static constexpr size_t OFF_DC    = 525312 + (size_t)F * N * KC * 2; // bf16 [F][N][KC]
static constexpr size_t ZERO_BYTES = 263168; // loss + both key arrays

typedef __attribute__((ext_vector_type(8))) short short8;
typedef __attribute__((ext_vector_type(4))) float f32x4;

__device__ __forceinline__ unsigned fmap(float x) {
    unsigned u = __float_as_uint(x);
    return (u & 0x80000000u) ? ~u : (u | 0x80000000u);
}
__device__ __forceinline__ float bf2f(ushort u) {
    return __uint_as_float(((unsigned)u) << 16);
}
__device__ __forceinline__ ushort f2bf(float x) {
    __hip_bfloat16 h = __float2bfloat16(x);   // RN
    return *(ushort*)&h;
}
__device__ __forceinline__ void gload_lds16(const void* g, void* l) {
    __builtin_amdgcn_global_load_lds(
        (const __attribute__((address_space(1))) void*)g,
        (__attribute__((address_space(3))) void*)l, 16, 0, 0);
}

// ---- pack: [2,N,D,F] -> Qcat/Dcat bf16 [F][N][KC]; 1/norm per (f,row) fp32 ----
__global__ __launch_bounds__(1024) void pack_kernel(
    const float* __restrict__ om, ushort* __restrict__ Qc, ushort* __restrict__ Dc,
    float* __restrict__ rnq, float* __restrict__ rnd) {
    __shared__ float buf[D * F];
    __shared__ float wsum[16];
    int b = blockIdx.x;           // 0 .. 2N-1
    int side = b >> 11;
    int i = b & (N - 1);
    int t = threadIdx.x;          // 0..1023
    buf[t] = om[(size_t)(side * N + i) * (D * F) + t];
    __syncthreads();
    int f = t >> 7, k = t & 127;
    float v = buf[k * F + f];
    ushort hi = f2bf(v);
    float hif = bf2f(hi);
    ushort lo = f2bf(v - hif);
    ushort* out = side ? Dc : Qc;
    size_t base = ((size_t)f * N + i) * KC;
    out[base + k]       = hi;
    out[base + 128 + k] = side ? lo : hi;
    out[base + 256 + k] = side ? hi : lo;
    float s = v * v;
    for (int off = 32; off >= 1; off >>= 1) s += __shfl_down(s, off, 64);
    if ((t & 63) == 0) wsum[t >> 6] = s;
    __syncthreads();
    if ((t & 127) == 0) {
        float tot = wsum[t >> 6] + wsum[(t >> 6) + 1];
        ((side == 0) ? rnq : rnd)[f * N + i] = 1.0f / sqrtf(tot);
    }
}

// ---- diag: one wave per row; dot over KC bf16 (same numeric path as sim) ----
__global__ __launch_bounds__(256) void diag_kernel(
    const ushort* __restrict__ Qc, const ushort* __restrict__ Dc,
    const float* __restrict__ rnq, const float* __restrict__ rnd,
    const float* __restrict__ label, float* __restrict__ diag_s, float* __restrict__ diag_l) {
    int row = blockIdx.x * 4 + (threadIdx.x >> 6);   // f*N + i
    int l = threadIdx.x & 63;
    const ushort* q = Qc + (size_t)row * KC;
    const ushort* d = Dc + (size_t)row * KC;
    float s = 0.f;
#pragma unroll
    for (int m = 0; m < 6; m++) {
        int k = l + m * 64;
        s += bf2f(q[k]) * bf2f(d[k]);
    }
    for (int off = 32; off >= 1; off >>= 1) s += __shfl_down(s, off, 64);
    if (l == 0) {
        diag_s[row] = s * rnq[row] * rnd[row];
        int f = row >> 11;
        int i = row & (N - 1);
        diag_l[row] = label[((size_t)f * N + i) * N + i];
    }
}

// ---- fused MFMA GEMM (128x128 tile, 4 waves of 64x64) + epilogue ----
__global__ __launch_bounds__(256, 3) void main_kernel(
    const ushort* __restrict__ Qc, const ushort* __restrict__ Dc,
    const float* __restrict__ label,
    const float* __restrict__ rnq, const float* __restrict__ rnd,
    const float* __restrict__ diag_s, const float* __restrict__ diag_l,
    const float* __restrict__ marginp,
    unsigned long long* __restrict__ keys_sim,
    unsigned long long* __restrict__ keys_lab,
    float* __restrict__ loss_acc) {
    __shared__ __align__(16) ushort As[128 * BK];
    __shared__ __align__(16) ushort Bs[128 * BK];
    const int f = blockIdx.z;
    const int i0 = blockIdx.y * 128;
    const int j0 = blockIdx.x * 128;
    const int t = threadIdx.x;
    const int lane = t & 63, wave = t >> 6;
    const int wy = wave >> 1, wx = wave & 1;
    const int lhi = lane >> 4, llo = lane & 15;

    f32x4 acc[4][4];
#pragma unroll
    for (int a = 0; a < 4; a++)
#pragma unroll
        for (int b = 0; b < 4; b++) acc[a][b] = (f32x4){0.f, 0.f, 0.f, 0.f};

    const char* Ag = (const char*)(Qc + ((size_t)f * N + i0) * KC);
    const char* Bg = (const char*)(Dc + ((size_t)f * N + j0) * KC);
    const int r = t >> 3;            // 0..31: row within 32-row group
    const int cb = (t & 7) * 16;     // byte column within 128B row chunk
    char* AsB = (char*)As;
    char* BsB = (char*)Bs;

    for (int k0 = 0; k0 < KC; k0 += BK) {
        const size_t gcol = (size_t)(k0 * 2 + cb);
#pragma unroll
        for (int p = 0; p < 4; p++) {
            gload_lds16(Ag + (size_t)(r + p * 32) * (KC * 2) + gcol, AsB + t * 16 + p * 4096);
            gload_lds16(Bg + (size_t)(r + p * 32) * (KC * 2) + gcol, BsB + t * 16 + p * 4096);
        }
        __syncthreads();   // drains vmcnt -> LDS valid
#pragma unroll
        for (int kk = 0; kk < BK; kk += 32) {
            short8 af[4], bfv[4];
#pragma unroll
            for (int x = 0; x < 4; x++) {
                af[x]  = *(const short8*)&As[(wy * 64 + x * 16 + llo) * BK + kk + lhi * 8];
                bfv[x] = *(const short8*)&Bs[(wx * 64 + x * 16 + llo) * BK + kk + lhi * 8];
            }
#pragma unroll
            for (int a = 0; a < 4; a++)
#pragma unroll
                for (int b = 0; b < 4; b++)
                    acc[a][b] = __builtin_amdgcn_mfma_f32_16x16x32_bf16(af[a], bfv[b], acc[a][b], 0, 0, 0);
        }
        __syncthreads();
    }

    // -------- epilogue: C/D layout col=lane&15, row=(lane>>4)*4+reg --------
    const float margin = *marginp;
    float loss = 0.f;
    const int jbase = j0 + wx * 64 + llo;
    float rdl[4];
#pragma unroll
    for (int b = 0; b < 4; b++) rdl[b] = rnd[f * N + jbase + b * 16];

#pragma unroll
    for (int a = 0; a < 4; a++) {
#pragma unroll
        for (int reg = 0; reg < 4; reg++) {
            const int i = i0 + wy * 64 + a * 16 + lhi * 4 + reg;
            const float rq = rnq[f * N + i];
            const float ds = diag_s[f * N + i];
            const float dl = diag_l[f * N + i];
            const float* lrow = label + ((size_t)f * N + i) * N;
            unsigned long long bestS = 0ull, bestL = 0ull;
#pragma unroll
            for (int b = 0; b < 4; b++) {
                const int j = jbase + b * 16;
                const float sim = acc[a][b][reg] * rq * rdl[b];
                const float lb = lrow[j];
                const float lm = margin - (ds - sim) * (dl - lb);
                loss += (j != i && lm > 0.f) ? lm : 0.f;
                unsigned long long ks = (((unsigned long long)fmap(sim)) << 32) | (unsigned long long)(0xFFFFFFFFu - (unsigned)j);
                unsigned long long kl = (((unsigned long long)fmap(lb)) << 32) | (unsigned long long)(0xFFFFFFFFu - (unsigned)j);
                bestS = (ks > bestS) ? ks : bestS;
                bestL = (kl > bestL) ? kl : bestL;
            }
#pragma unroll
            for (int off = 1; off < 16; off <<= 1) {
                unsigned long long oS = __shfl_xor(bestS, off, 64);
                unsigned long long oL = __shfl_xor(bestL, off, 64);
                bestS = (oS > bestS) ? oS : bestS;
                bestL = (oL > bestL) ? oL : bestL;
            }
            if (llo == 0) {
                atomicMax(&keys_sim[f * N + i], bestS);
                atomicMax(&keys_lab[f * N + i], bestL);
            }
        }
    }

    for (int off = 32; off >= 1; off >>= 1) loss += __shfl_down(loss, off, 64);
    __shared__ float lred[4];
    if ((t & 63) == 0) lred[t >> 6] = loss;
    __syncthreads();
    if (t == 0) atomicAdd(loss_acc, lred[0] + lred[1] + lred[2] + lred[3]);
}

// ---- final: count argmax matches, write outputs ----
__global__ __launch_bounds__(256) void final_kernel(
    const unsigned long long* __restrict__ keys_sim,
    const unsigned long long* __restrict__ keys_lab,
    const float* __restrict__ loss_acc, float* __restrict__ out) {
    int t = threadIdx.x;
    int cnt = 0;
    for (int r = t; r < F * N; r += 256) {
        unsigned js = 0xFFFFFFFFu - (unsigned)(keys_sim[r] & 0xFFFFFFFFull);
        unsigned jl = 0xFFFFFFFFu - (unsigned)(keys_lab[r] & 0xFFFFFFFFull);
        cnt += (js == jl) ? 1 : 0;
    }
    for (int off = 32; off >= 1; off >>= 1) cnt += __shfl_down(cnt, off, 64);
    __shared__ int cred[4];
    if ((t & 63) == 0) cred[t >> 6] = cnt;
    __syncthreads();
    if (t == 0) {
        out[0] = *loss_acc;
        out[1] = (float)(cred[0] + cred[1] + cred[2] + cred[3]);
    }
}

extern "C" void kernel_launch(void* const* d_in, const int* in_sizes, int n_in,
                              void* d_out, int out_size, void* d_ws, size_t ws_size,
                              hipStream_t stream) {
    const float* om     = (const float*)d_in[0];   // [2,N,D,F]
    const float* label  = (const float*)d_in[1];   // [F,N,N]
    const float* margin = (const float*)d_in[2];   // scalar
    (void)in_sizes; (void)n_in; (void)out_size; (void)ws_size;

    char* ws = (char*)d_ws;
    float*              loss_acc = (float*)(ws + OFF_LOSS);
    unsigned long long* keys_sim = (unsigned long long*)(ws + OFF_KSIM);
    unsigned long long* keys_lab = (unsigned long long*)(ws + OFF_KLAB);
    float* rnq    = (float*)(ws + OFF_RNQ);
    float* rnd    = (float*)(ws + OFF_RND);
    float* diag_s = (float*)(ws + OFF_DIAGS);
    float* diag_l = (float*)(ws + OFF_DIAGL);
    ushort* Qc    = (ushort*)(ws + OFF_QC);
    ushort* Dc    = (ushort*)(ws + OFF_DC);

    hipMemsetAsync(ws, 0, ZERO_BYTES, stream);  // zero loss + argmax keys

    pack_kernel<<<2 * N, 1024, 0, stream>>>(om, Qc, Dc, rnq, rnd);
    diag_kernel<<<F * N / 4, 256, 0, stream>>>(Qc, Dc, rnq, rnd, label, diag_s, diag_l);

    dim3 grid(N / 128, N / 128, F);
    main_kernel<<<grid, 256, 0, stream>>>(Qc, Dc, label, rnq, rnd, diag_s, diag_l,
                                          margin, keys_sim, keys_lab, loss_acc);

    final_kernel<<<1, 256, 0, stream>>>(keys_sim, keys_lab, loss_acc, (float*)d_out);
}

// Round 3
// 280.054 us; speedup vs baseline: 1.2776x; 1.2776x over previous
//
#include <hip/hip_runtime.h>
#include <hip/hip_bf16.h>

static constexpr int N = 2048;
static constexpr int D = 128;
static constexpr int F = 8;
static constexpr int KC = 384;   // concat K: [hi|hi|lo] x [hi|lo|hi] = hh+hl+lh
static constexpr int BK = 64;

// ---------------- workspace layout (bytes) ----------------
static constexpr size_t OFF_LOSS  = 0;
static constexpr size_t OFF_KSIM  = 1024;
static constexpr size_t OFF_KLAB  = 132096;
static constexpr size_t OFF_RNQ   = 263168;
static constexpr size_t OFF_RND   = 328704;
static constexpr size_t OFF_DIAGS = 394240;
static constexpr size_t OFF_DIAGL = 459776;
static constexpr size_t OFF_QC    = 525312;                          // bf16 [F][N][KC]
static constexpr size_t OFF_DC    = 525312 + (size_t)F * N * KC * 2; // bf16 [F][N][KC]
static constexpr size_t ZERO_BYTES = 263168; // loss + both key arrays

typedef __attribute__((ext_vector_type(8))) short short8;
typedef __attribute__((ext_vector_type(4))) float f32x4;
typedef unsigned long long u64;

__device__ __forceinline__ unsigned fmap(float x) {
    unsigned u = __float_as_uint(x);
    return (u & 0x80000000u) ? ~u : (u | 0x80000000u);
}
__device__ __forceinline__ float bf2f(ushort u) {
    return __uint_as_float(((unsigned)u) << 16);
}
__device__ __forceinline__ ushort f2bf(float x) {
    __hip_bfloat16 h = __float2bfloat16(x);   // RN
    return *(ushort*)&h;
}
__device__ __forceinline__ void gload_lds16(const void* g, void* l) {
    __builtin_amdgcn_global_load_lds(
        (const __attribute__((address_space(1))) void*)g,
        (__attribute__((address_space(3))) void*)l, 16, 0, 0);
}

// ---- pack + norms + diag (fused): [2,N,D,F] -> Qcat/Dcat bf16 [F][N][KC] ----
__global__ __launch_bounds__(1024) void pack_kernel(
    const float* __restrict__ om, const float* __restrict__ label,
    ushort* __restrict__ Qc, ushort* __restrict__ Dc,
    float* __restrict__ rnq, float* __restrict__ rnd,
    float* __restrict__ diag_s, float* __restrict__ diag_l) {
    __shared__ float buf0[D * F];
    __shared__ float buf1[D * F];
    __shared__ float wred[3][16];
    const int i = blockIdx.x;     // row 0..N-1
    const int t = threadIdx.x;    // 0..1023
    buf0[t] = om[(size_t)i * (D * F) + t];
    buf1[t] = om[(size_t)(N + i) * (D * F) + t];
    __syncthreads();
    const int f = t >> 7, k = t & 127;
    const float v0 = buf0[k * F + f];
    const float v1 = buf1[k * F + f];
    const ushort h0 = f2bf(v0); const ushort l0 = f2bf(v0 - bf2f(h0));
    const ushort h1 = f2bf(v1); const ushort l1 = f2bf(v1 - bf2f(h1));
    const size_t base = ((size_t)f * N + i) * KC;
    Qc[base + k] = h0; Qc[base + 128 + k] = h0; Qc[base + 256 + k] = l0;
    Dc[base + k] = h1; Dc[base + 128 + k] = l1; Dc[base + 256 + k] = h1;
    float s0 = v0 * v0, s1 = v1 * v1, p = v0 * v1;
    for (int off = 32; off >= 1; off >>= 1) {
        s0 += __shfl_down(s0, off, 64);
        s1 += __shfl_down(s1, off, 64);
        p  += __shfl_down(p,  off, 64);
    }
    if ((t & 63) == 0) {
        int w = t >> 6;
        wred[0][w] = s0; wred[1][w] = s1; wred[2][w] = p;
    }
    __syncthreads();
    if ((t & 127) == 0) {
        int w = t >> 6;
        float S0 = wred[0][w] + wred[0][w + 1];
        float S1 = wred[1][w] + wred[1][w + 1];
        float P  = wred[2][w] + wred[2][w + 1];
        float rq = 1.0f / sqrtf(S0), rd = 1.0f / sqrtf(S1);
        rnq[f * N + i] = rq;
        rnd[f * N + i] = rd;
        diag_s[f * N + i] = P * rq * rd;
        diag_l[f * N + i] = label[((size_t)f * N + i) * N + i];
    }
}

// ---- fused MFMA GEMM (128x128 tile; wave = 32 rows x 128 cols) + epilogue ----
// LDS rows are 128B (BK=64 bf16); 16B chunk position XOR-swizzled by (row&7)
// so ds_read_b128 fragment reads are conflict-free (2-way only).
__global__ __launch_bounds__(256, 3) void main_kernel(
    const ushort* __restrict__ Qc, const ushort* __restrict__ Dc,
    const float* __restrict__ label,
    const float* __restrict__ rnq, const float* __restrict__ rnd,
    const float* __restrict__ diag_s, const float* __restrict__ diag_l,
    const float* __restrict__ marginp,
    u64* __restrict__ keys_sim, u64* __restrict__ keys_lab,
    float* __restrict__ loss_acc) {
    __shared__ __align__(16) char smem[34816];
    ushort* As = (ushort*)smem;             // [128][64] bf16 (swizzled)
    ushort* Bs = (ushort*)(smem + 16384);   // [128][64]
    u64* kbS = (u64*)smem;                  // [128][17] aliases As/Bs after K-loop
    u64* kbL = (u64*)(smem + 17408);        // [128][17]
    __shared__ float lred[4];

    const int f = blockIdx.z;
    const int i0 = blockIdx.y * 128;
    const int j0 = blockIdx.x * 128;
    const int t = threadIdx.x;
    const int lane = t & 63, wave = t >> 6;
    const int lhi = lane >> 4, llo = lane & 15;

    f32x4 acc[2][8];
#pragma unroll
    for (int a = 0; a < 2; a++)
#pragma unroll
        for (int b = 0; b < 8; b++) acc[a][b] = (f32x4){0.f, 0.f, 0.f, 0.f};

    const char* Ag = (const char*)(Qc + ((size_t)f * N + i0) * KC);
    const char* Bg = (const char*)(Dc + ((size_t)f * N + j0) * KC);
    char* AsB = (char*)As;
    char* BsB = (char*)Bs;
    const int srow = t >> 3;     // 0..31
    const int schunk = t & 7;    // 16B chunk index

    for (int k0 = 0; k0 < KC; k0 += BK) {
#pragma unroll
        for (int p = 0; p < 4; p++) {
            const int row = srow + p * 32;
            const int gc = schunk ^ (row & 7);
            const size_t goff = (size_t)row * (KC * 2) + (size_t)(k0 * 2 + gc * 16);
            gload_lds16(Ag + goff, AsB + t * 16 + p * 4096);
            gload_lds16(Bg + goff, BsB + t * 16 + p * 4096);
        }
        __syncthreads();   // drains vmcnt -> LDS valid
#pragma unroll
        for (int kk = 0; kk < BK; kk += 32) {
            const int kc = kk >> 3;   // logical 16B chunk base (0 or 4)
            short8 af[2], bfv[8];
#pragma unroll
            for (int a = 0; a < 2; a++) {
                const int R = wave * 32 + a * 16 + llo;
                af[a] = *(const short8*)&As[R * 64 + (((kc + lhi) ^ (R & 7)) * 8)];
            }
#pragma unroll
            for (int b = 0; b < 8; b++) {
                const int R = b * 16 + llo;
                bfv[b] = *(const short8*)&Bs[R * 64 + (((kc + lhi) ^ (R & 7)) * 8)];
            }
#pragma unroll
            for (int a = 0; a < 2; a++)
#pragma unroll
                for (int b = 0; b < 8; b++)
                    acc[a][b] = __builtin_amdgcn_mfma_f32_16x16x32_bf16(af[a], bfv[b], acc[a][b], 0, 0, 0);
        }
        __syncthreads();
    }

    // -------- epilogue: C/D layout col=lane&15, row=(lane>>4)*4+reg --------
    const float margin = *marginp;
    float loss = 0.f;
    float rdl[8];
#pragma unroll
    for (int b = 0; b < 8; b++) rdl[b] = rnd[f * N + j0 + b * 16 + llo];

#pragma unroll
    for (int a = 0; a < 2; a++) {
#pragma unroll
        for (int reg = 0; reg < 4; reg++) {
            const int rloc = wave * 32 + a * 16 + lhi * 4 + reg;
            const int i = i0 + rloc;
            const float rq = rnq[f * N + i];
            const float ds = diag_s[f * N + i];
            const float dl = diag_l[f * N + i];
            const float* lrow = label + ((size_t)f * N + i) * N + j0;
            u64 bestS = 0ull, bestL = 0ull;
#pragma unroll
            for (int b = 0; b < 8; b++) {
                const int j = j0 + b * 16 + llo;
                const float sim = acc[a][b][reg] * rq * rdl[b];
                const float lb = lrow[b * 16 + llo];
                const float lm = margin - (ds - sim) * (dl - lb);
                loss += (j != i && lm > 0.f) ? lm : 0.f;
                u64 ks = (((u64)fmap(sim)) << 32) | (u64)(0xFFFFFFFFu - (unsigned)j);
                u64 kl = (((u64)fmap(lb)) << 32) | (u64)(0xFFFFFFFFu - (unsigned)j);
                bestS = (ks > bestS) ? ks : bestS;
                bestL = (kl > bestL) ? kl : bestL;
            }
            kbS[rloc * 17 + llo] = bestS;
            kbL[rloc * 17 + llo] = bestL;
        }
    }
    __syncthreads();
    // row reduction: threads 0..127 handle sim keys, 128..255 label keys
    {
        const int r = t & 127;
        const u64* kb = (t < 128) ? kbS : kbL;
        u64 best = 0ull;
#pragma unroll
        for (int k = 0; k < 16; k++) {
            u64 v = kb[r * 17 + k];
            best = (v > best) ? v : best;
        }
        u64* dst = (t < 128) ? &keys_sim[f * N + i0 + r] : &keys_lab[f * N + i0 + r];
        atomicMax(dst, best);
    }

    for (int off = 32; off >= 1; off >>= 1) loss += __shfl_down(loss, off, 64);
    if ((t & 63) == 0) lred[t >> 6] = loss;
    __syncthreads();
    if (t == 0) atomicAdd(loss_acc, lred[0] + lred[1] + lred[2] + lred[3]);
}

// ---- final: count argmax matches, write outputs ----
__global__ __launch_bounds__(1024) void final_kernel(
    const u64* __restrict__ keys_sim, const u64* __restrict__ keys_lab,
    const float* __restrict__ loss_acc, float* __restrict__ out) {
    int t = threadIdx.x;
    int cnt = 0;
    for (int r = t; r < F * N; r += 1024) {
        unsigned js = (unsigned)(keys_sim[r] & 0xFFFFFFFFull);
        unsigned jl = (unsigned)(keys_lab[r] & 0xFFFFFFFFull);
        cnt += (js == jl) ? 1 : 0;
    }
    for (int off = 32; off >= 1; off >>= 1) cnt += __shfl_down(cnt, off, 64);
    __shared__ int cred[16];
    if ((t & 63) == 0) cred[t >> 6] = cnt;
    __syncthreads();
    if (t == 0) {
        int tot = 0;
#pragma unroll
        for (int w = 0; w < 16; w++) tot += cred[w];
        out[0] = *loss_acc;
        out[1] = (float)tot;
    }
}

extern "C" void kernel_launch(void* const* d_in, const int* in_sizes, int n_in,
                              void* d_out, int out_size, void* d_ws, size_t ws_size,
                              hipStream_t stream) {
    const float* om     = (const float*)d_in[0];   // [2,N,D,F]
    const float* label  = (const float*)d_in[1];   // [F,N,N]
    const float* margin = (const float*)d_in[2];   // scalar
    (void)in_sizes; (void)n_in; (void)out_size; (void)ws_size;

    char* ws = (char*)d_ws;
    float* loss_acc = (float*)(ws + OFF_LOSS);
    u64*   keys_sim = (u64*)(ws + OFF_KSIM);
    u64*   keys_lab = (u64*)(ws + OFF_KLAB);
    float* rnq    = (float*)(ws + OFF_RNQ);
    float* rnd    = (float*)(ws + OFF_RND);
    float* diag_s = (float*)(ws + OFF_DIAGS);
    float* diag_l = (float*)(ws + OFF_DIAGL);
    ushort* Qc    = (ushort*)(ws + OFF_QC);
    ushort* Dc    = (ushort*)(ws + OFF_DC);

    hipMemsetAsync(ws, 0, ZERO_BYTES, stream);  // zero loss + argmax keys

    pack_kernel<<<N, 1024, 0, stream>>>(om, label, Qc, Dc, rnq, rnd, diag_s, diag_l);

    dim3 grid(N / 128, N / 128, F);
    main_kernel<<<grid, 256, 0, stream>>>(Qc, Dc, label, rnq, rnd, diag_s, diag_l,
                                          margin, keys_sim, keys_lab, loss_acc);

    final_kernel<<<1, 1024, 0, stream>>>(keys_sim, keys_lab, loss_acc, (float*)d_out);
}